// Round 1
// 1610.708 us; speedup vs baseline: 1.0284x; 1.0284x over previous
//
#include <hip/hip_runtime.h>

// ---------------------------------------------------------------------------
// Two-layer tanh RNN — concurrent-layer persistent kernel (grid-axis fusion).
// B=64, T=512, H=512, I=128, W_OUT=32. fp32 in/out, f16-pair internal, fp32 acc.
//
// One dispatch, 512 WGs x 256 (launch_bounds(256,2) => all co-resident):
//   layer = blockIdx&1; 256 WGs per layer = 8 row-groups x 32 batch-pairs.
// Round-3 change: wave-uniform chunk mapping. A WAVE owns one K-chunk
//   (c = L>>6), a LANE owns one row (r = wgr*64 + (L&63)). All 64 lanes of a
//   wave read the SAME hv address per ds_read_b128 -> single-address LDS
//   broadcast (16B/instr) instead of 4-address (64B/instr). K-reduce moved
//   from shfl_xor(1,2) to cross-wave LDS psum reduce (waves 0/1 finish rows
//   for batch 0/1: tanh+pack+post done once per row, not 4x).
// Exchange (unchanged): 64-bit {tag|f16pair} atoms, RELAXED agent scope.
//   hbuf0: 256-step ring (layer-0 posts; layer-0 self-gather + layer-1 gather).
//   hbuf1: 4-step ring (layer-1 self-recurrence).
// Layer-1 trails layer-0 by ~1 step; total ~= T*step instead of 2*T*step.
// FC epilogue fused into layer-1 wgr==0 WGs.
// ---------------------------------------------------------------------------

#define T_STEPS 512
#define NBATCH  64
#define DRING   256

typedef _Float16 half2v __attribute__((ext_vector_type(2)));

__device__ __forceinline__ unsigned pack2(float a, float b) {
    _Float16 fa = (_Float16)a, fb = (_Float16)b;
    unsigned short ua = __builtin_bit_cast(unsigned short, fa);
    unsigned short ub = __builtin_bit_cast(unsigned short, fb);
    return (unsigned)ua | ((unsigned)ub << 16);
}

__device__ __forceinline__ float dot2acc(unsigned w, unsigned h, float acc) {
#if __has_builtin(__builtin_amdgcn_fdot2)
    return __builtin_amdgcn_fdot2(__builtin_bit_cast(half2v, w),
                                  __builtin_bit_cast(half2v, h), acc, false);
#else
    half2v wv = __builtin_bit_cast(half2v, w);
    half2v hv = __builtin_bit_cast(half2v, h);
    acc = fmaf((float)wv.x, (float)hv.x, acc);
    return fmaf((float)wv.y, (float)hv.y, acc);
#endif
}

__device__ __forceinline__ float fast_tanh(float xv) {
    float e2 = __builtin_amdgcn_exp2f(xv * 2.885390082f);
    return 1.f - 2.f * __builtin_amdgcn_rcpf(e2 + 1.f);
}

// Poll N tagged atoms concurrently (overlapped RTTs), relaxed agent scope.
template <int N>
__device__ __forceinline__ void pollN(unsigned long long* const (&p)[N],
                                      const unsigned (&tag)[N],
                                      unsigned (&res)[N], long& budget) {
    bool done[N];
#pragma unroll
    for (int i = 0; i < N; ++i) done[i] = false;
    int remaining = N;
    while (remaining > 0 && budget > 0) {
        unsigned long long v[N];
#pragma unroll
        for (int i = 0; i < N; ++i)
            if (!done[i])
                v[i] = __hip_atomic_load(p[i], __ATOMIC_RELAXED, __HIP_MEMORY_SCOPE_AGENT);
#pragma unroll
        for (int i = 0; i < N; ++i)
            if (!done[i] && (unsigned)(v[i] >> 32) == tag[i]) {
                res[i] = (unsigned)v[i]; done[i] = true; --remaining;
            }
        --budget;
    }
}

// Packed-weight layouts [wgr<8][j<P][lane<256].
// Round-3 mapping: r = wg*64 + (L&63), c = L>>6 (wave-uniform chunk).
#define N0 (8 * 80 * 256)
#define N1 (8 * 128 * 256)

__global__ void init_pack(const float* __restrict__ Wih0, const float* __restrict__ Whh0,
                          const float* __restrict__ Wih1, const float* __restrict__ Whh1,
                          unsigned* __restrict__ wp0, unsigned* __restrict__ wp1) {
    int gid = blockIdx.x * 256 + threadIdx.x;
    if (gid < N0) {
        int L = gid & 255; int j = (gid >> 8) % 80; int wg = (gid >> 8) / 80;
        int r = wg * 64 + (L & 63); int c = L >> 6; int k = c * 160 + 2 * j;
        float w0 = (k < 128) ? Wih0[r * 128 + k]     : Whh0[r * 512 + (k - 128)];
        float w1 = (k + 1 < 128) ? Wih0[r * 128 + k + 1] : Whh0[r * 512 + (k - 127)];
        wp0[gid] = pack2(w0, w1);
    } else {
        int g2 = gid - N0;
        if (g2 < N1) {
            int L = g2 & 255; int j = (g2 >> 8) % 128; int wg = (g2 >> 8) / 128;
            int r = wg * 64 + (L & 63); int c = L >> 6; int k = c * 256 + 2 * j;
            float w0 = (k < 512) ? Wih1[r * 512 + k]     : Whh1[r * 512 + (k - 512)];
            float w1 = (k + 1 < 512) ? Wih1[r * 512 + k + 1] : Whh1[r * 512 + (k - 511)];
            wp1[g2] = pack2(w0, w1);
        }
    }
}

// PW: f16-pairs per lane (80 or 128). KIN: non-recurrent width (128 or 512).
template <int PW, int KIN, int LAYER>
__device__ __forceinline__ void run_layer(
    int b0, int wgr, int L,
    const float* __restrict__ x, const float* __restrict__ noise,
    const unsigned* __restrict__ wpack,
    const float* __restrict__ bih, const float* __restrict__ bhh,
    unsigned long long* __restrict__ hbuf0,
    unsigned long long* __restrict__ hbuf1,
    const float* __restrict__ fcw, const float* __restrict__ fcb,
    float* __restrict__ out) {
    constexpr int CH = PW + 4;           // LDS chunk stride (16B-aligned: (PW+4)*4 % 16 == 0)
    const int c = L >> 6;                // wave id == K-chunk id (wave-uniform)
    const int lane = L & 63;
    const int r = wgr * 64 + lane;       // lane owns a full row

    unsigned wreg[PW];
#pragma unroll
    for (int j = 0; j < PW; ++j) {
        wreg[j] = wpack[(wgr * PW + j) * 256 + L];
        asm volatile("" : "+v"(wreg[j]));
    }

    const float cb = bih[r] + bhh[r];

    __shared__ __align__(16) unsigned hv[2][4][CH];
    __shared__ float psum[4][2][64];     // [chunk][batch][row-lane]
    for (int i = L; i < 2 * 4 * CH; i += 256) ((unsigned*)hv)[i] = 0u;  // h(-1)=0
    __syncthreads();

    long budget = 2000000000L;           // hang bailout only

    // t=0 input region
    if constexpr (LAYER == 0) {
        if (L < 128) {
            int bb = L >> 6, j = L & 63;
            float2 xf = *(const float2*)(x + ((size_t)(b0 + bb) * T_STEPS) * 128 + 2 * j);
            hv[bb][j / PW][j % PW] = pack2(xf.x, xf.y);
        }
    } else {
        unsigned long long* p[2]; unsigned tg[2], res[2];
#pragma unroll
        for (int bb = 0; bb < 2; ++bb) {
            p[bb] = &hbuf0[((size_t)0 * NBATCH + (b0 + bb)) * 256 + L];
            tg[bb] = 1u;
        }
        pollN<2>(p, tg, res, budget);
#pragma unroll
        for (int bb = 0; bb < 2; ++bb) hv[bb][L >> 7][L & 127] = res[bb];
    }
    __syncthreads();

    float nz[2];
#pragma unroll
    for (int bb = 0; bb < 2; ++bb)
        nz[bb] = noise[(((size_t)(b0 + bb) * T_STEPS) * 2 + LAYER) * 512 + r];

    for (int t = 0; t < T_STEPS; ++t) {
        // ---- dot partials: wave c handles chunk c for all 64 rows ----
#pragma unroll
        for (int bb = 0; bb < 2; ++bb) {
            const uint4* hq = (const uint4*)(&hv[bb][c][0]);   // wave-uniform address
            float a0 = 0.f, a1 = 0.f, a2 = 0.f, a3 = 0.f;
#pragma unroll
            for (int jj = 0; jj < PW / 4; ++jj) {
                uint4 hp = hq[jj];
                a0 = dot2acc(wreg[4 * jj + 0], hp.x, a0);
                a1 = dot2acc(wreg[4 * jj + 1], hp.y, a1);
                a2 = dot2acc(wreg[4 * jj + 2], hp.z, a2);
                a3 = dot2acc(wreg[4 * jj + 3], hp.w, a3);
            }
            psum[c][bb][lane] = (a0 + a1) + (a2 + a3);
        }

        const bool last = (t == T_STEPS - 1);

        // prefetch next-step inputs before the barrier (overlap HBM latency)
        float2 xf;
        float nznext[2];
        if (!last) {
            if constexpr (LAYER == 0) {
                if (L < 128) {
                    int bb = L >> 6, j = L & 63;
                    xf = *(const float2*)(x + ((size_t)(b0 + bb) * T_STEPS + (t + 1)) * 128 + 2 * j);
                }
            }
#pragma unroll
            for (int bb = 0; bb < 2; ++bb)
                nznext[bb] = noise[(((size_t)(b0 + bb) * T_STEPS + (t + 1)) * 2 + LAYER) * 512 + r];
        }

        __syncthreads();                 // psum ready; this step's hv reads complete

        // ---- cross-wave reduce + tanh + post: wave bb finishes batch bb ----
        if (c < 2) {
            const int bb = c;
            float s = psum[0][bb][lane] + psum[1][bb][lane] +
                      psum[2][bb][lane] + psum[3][bb][lane];
            float nzsel = (c == 0) ? nz[0] : nz[1];
            float h = fast_tanh(s + cb + nzsel);
            float hnb = __shfl_down(h, 1);
            if ((lane & 1) == 0) {
                unsigned pv = pack2(h, hnb);
                unsigned long long atom =
                    ((unsigned long long)(unsigned)(t + 1) << 32) | (unsigned long long)pv;
                const int pr = r >> 1;   // pair index wgr*32 + lane/2
                if constexpr (LAYER == 0)
                    __hip_atomic_store(
                        &hbuf0[((size_t)(t & (DRING - 1)) * NBATCH + (b0 + bb)) * 256 + pr],
                        atom, __ATOMIC_RELAXED, __HIP_MEMORY_SCOPE_AGENT);
                else
                    __hip_atomic_store(
                        &hbuf1[((size_t)(t & 3) * NBATCH + (b0 + bb)) * 256 + pr],
                        atom, __ATOMIC_RELAXED, __HIP_MEMORY_SCOPE_AGENT);
            }
        }

        if (last) break;

        nz[0] = nznext[0]; nz[1] = nznext[1];

        // ---- gather h(t) back (poll tagged atoms), place into hv ----
        if constexpr (LAYER == 0) {
            unsigned long long* p[2]; unsigned tg[2], res[2];
#pragma unroll
            for (int bb = 0; bb < 2; ++bb) {
                p[bb] = &hbuf0[((size_t)(t & (DRING - 1)) * NBATCH + (b0 + bb)) * 256 + L];
                tg[bb] = (unsigned)(t + 1);
            }
            pollN<2>(p, tg, res, budget);
#pragma unroll
            for (int bb = 0; bb < 2; ++bb) {
                int q = 64 + L;                          // recurrent pair index
                hv[bb][q / PW][q % PW] = res[bb];
            }
            if (L < 128) {
                int bb = L >> 6, j = L & 63;
                hv[bb][j / PW][j % PW] = pack2(xf.x, xf.y);
            }
        } else {
            unsigned long long* p[4]; unsigned tg[4], res[4];
#pragma unroll
            for (int bb = 0; bb < 2; ++bb) {
                p[bb] = &hbuf1[((size_t)(t & 3) * NBATCH + (b0 + bb)) * 256 + L];
                tg[bb] = (unsigned)(t + 1);              // h1(t) self-recurrence
                p[2 + bb] = &hbuf0[((size_t)((t + 1) & (DRING - 1)) * NBATCH + (b0 + bb)) * 256 + L];
                tg[2 + bb] = (unsigned)(t + 2);          // h0(t+1) from layer-0
            }
            pollN<4>(p, tg, res, budget);
#pragma unroll
            for (int bb = 0; bb < 2; ++bb) {
                int q = 256 + L;                         // h1 pairs -> chunks 2,3
                hv[bb][q >> 7][q & 127] = res[bb];
                hv[bb][L >> 7][L & 127] = res[2 + bb];   // h0 pairs -> chunks 0,1
            }
        }
        __syncthreads();
    }

    if constexpr (LAYER == 1) {
        __shared__ float hs[2][512];
        __shared__ float part[2][256];
        if (wgr == 0) {                  // FC epilogue: out = h1(T-1) @ fc_w^T + fc_b
            unsigned long long* p[2]; unsigned tg[2], res[2];
#pragma unroll
            for (int bb = 0; bb < 2; ++bb) {
                p[bb] = &hbuf1[((size_t)((T_STEPS - 1) & 3) * NBATCH + (b0 + bb)) * 256 + L];
                tg[bb] = (unsigned)T_STEPS;
            }
            pollN<2>(p, tg, res, budget);
#pragma unroll
            for (int bb = 0; bb < 2; ++bb) {
                half2v h2 = __builtin_bit_cast(half2v, res[bb]);
                hs[bb][2 * L] = (float)h2.x; hs[bb][2 * L + 1] = (float)h2.y;
            }
            __syncthreads();
            const int o = L & 31, seg = L >> 5;          // 32 outputs x 8 k-segments
#pragma unroll
            for (int bb = 0; bb < 2; ++bb) {
                const float* wr = fcw + o * 512 + seg * 64;
                const float* hr = &hs[bb][seg * 64];
                float a = 0.f;
#pragma unroll 16
                for (int k = 0; k < 64; ++k) a = fmaf(wr[k], hr[k], a);
                part[bb][L] = a;
            }
            __syncthreads();
            if (L < 64) {
                int bb = L >> 5, oo = L & 31;
                float s = fcb[oo];
#pragma unroll
                for (int sgi = 0; sgi < 8; ++sgi) s += part[bb][sgi * 32 + oo];
                out[(b0 + bb) * 32 + oo] = s;
            }
        }
    }
}

__global__ __launch_bounds__(256, 2)
void rnn_dual(const float* __restrict__ x, const float* __restrict__ noise,
              const unsigned* __restrict__ wp0, const unsigned* __restrict__ wp1,
              const float* __restrict__ bih0, const float* __restrict__ bhh0,
              const float* __restrict__ bih1, const float* __restrict__ bhh1,
              const float* __restrict__ fcw, const float* __restrict__ fcb,
              unsigned long long* __restrict__ hbuf0,
              unsigned long long* __restrict__ hbuf1,
              float* __restrict__ out) {
    const int L = threadIdx.x;
    const int gid = blockIdx.x;
    const int layer = gid & 1;           // XCD = (2g+layer)%8 under rr dispatch:
    const int rest = gid >> 1;           //   all 8 row-WGs of (g,layer) share an XCD
    const int g = rest & 31;
    const int wgr = rest >> 5;
    const int b0 = g * 2;
    if (layer == 0)
        run_layer<80, 128, 0>(b0, wgr, L, x, noise, wp0, bih0, bhh0,
                              hbuf0, hbuf1, nullptr, nullptr, nullptr);
    else
        run_layer<128, 512, 1>(b0, wgr, L, x, noise, wp1, bih1, bhh1,
                               hbuf0, hbuf1, fcw, fcb, out);
}

extern "C" void kernel_launch(void* const* d_in, const int* in_sizes, int n_in,
                              void* d_out, int out_size, void* d_ws, size_t ws_size,
                              hipStream_t stream) {
    const float* x     = (const float*)d_in[0];
    const float* noise = (const float*)d_in[1];
    const float* Wih0  = (const float*)d_in[2];
    const float* Wih1  = (const float*)d_in[3];
    const float* Whh0  = (const float*)d_in[4];
    const float* Whh1  = (const float*)d_in[5];
    const float* bih0  = (const float*)d_in[6];
    const float* bih1  = (const float*)d_in[7];
    const float* bhh0  = (const float*)d_in[8];
    const float* bhh1  = (const float*)d_in[9];
    const float* fcw   = (const float*)d_in[10];
    const float* fcb   = (const float*)d_in[11];
    float* out = (float*)d_out;

    char* ws = (char*)d_ws;
    size_t o = 0;
    unsigned* wp0 = (unsigned*)(ws + o); o += (size_t)N0 * 4;   // 640 KB
    unsigned* wp1 = (unsigned*)(ws + o); o += (size_t)N1 * 4;   // 1 MB
    unsigned long long* hb0 = (unsigned long long*)(ws + o);
    o += (size_t)DRING * NBATCH * 256 * 8;                      // 33.5 MB ring
    unsigned long long* hb1 = (unsigned long long*)(ws + o);
    o += (size_t)4 * NBATCH * 256 * 8;                          // 512 KB ring

    const int initBlocks = (N0 + N1 + 255) / 256;
    init_pack<<<initBlocks, 256, 0, stream>>>(Wih0, Whh0, Wih1, Whh1, wp0, wp1);
    rnn_dual<<<512, 256, 0, stream>>>(x, noise, wp0, wp1, bih0, bhh0, bih1, bhh1,
                                      fcw, fcb, hb0, hb1, out);
}

// Round 2
// 1561.742 us; speedup vs baseline: 1.0607x; 1.0314x over previous
//
#include <hip/hip_runtime.h>

// ---------------------------------------------------------------------------
// Two-layer tanh RNN — concurrent-layer persistent kernel (grid-axis fusion).
// B=64, T=512, H=512, I=128, W_OUT=32. fp32 in/out, f16-pair internal, fp32 acc.
//
// One dispatch, 512 WGs x 256 (launch_bounds(256,2) => all co-resident):
//   layer = blockIdx&1; 256 WGs per layer = 8 row-groups x 32 batch-pairs.
// Wave-uniform chunk mapping (round 3): wave owns K-chunk (c=L>>6), lane owns
//   row (r=wgr*64+(L&63)); hv reads are single-address LDS broadcasts.
// Round-4 changes:
//   (a) s_setprio(1) around compute (dots/reduce/post/place), s_setprio(0)
//       around poll spins — co-resident WGs' spin loops no longer steal issue
//       slots from compute waves (anti-convoy).
//   (b) L1 prefetches h0(t+1) atoms into registers at the top of each step
//       (L0 leads by many steps; tag almost always already set) — the MALL RTT
//       overlaps the dot phase; blocking poll handles only the 2 self atoms.
// Exchange (unchanged): 64-bit {tag|f16pair} atoms, RELAXED agent scope.
//   hbuf0: 256-step ring (layer-0 posts; layer-0 self-gather + layer-1 gather).
//   hbuf1: 4-step ring (layer-1 self-recurrence).
// FC epilogue fused into layer-1 wgr==0 WGs.
// ---------------------------------------------------------------------------

#define T_STEPS 512
#define NBATCH  64
#define DRING   256

typedef _Float16 half2v __attribute__((ext_vector_type(2)));

__device__ __forceinline__ unsigned pack2(float a, float b) {
    _Float16 fa = (_Float16)a, fb = (_Float16)b;
    unsigned short ua = __builtin_bit_cast(unsigned short, fa);
    unsigned short ub = __builtin_bit_cast(unsigned short, fb);
    return (unsigned)ua | ((unsigned)ub << 16);
}

__device__ __forceinline__ float dot2acc(unsigned w, unsigned h, float acc) {
#if __has_builtin(__builtin_amdgcn_fdot2)
    return __builtin_amdgcn_fdot2(__builtin_bit_cast(half2v, w),
                                  __builtin_bit_cast(half2v, h), acc, false);
#else
    half2v wv = __builtin_bit_cast(half2v, w);
    half2v hv = __builtin_bit_cast(half2v, h);
    acc = fmaf((float)wv.x, (float)hv.x, acc);
    return fmaf((float)wv.y, (float)hv.y, acc);
#endif
}

__device__ __forceinline__ float fast_tanh(float xv) {
    float e2 = __builtin_amdgcn_exp2f(xv * 2.885390082f);
    return 1.f - 2.f * __builtin_amdgcn_rcpf(e2 + 1.f);
}

// Poll N tagged atoms concurrently (overlapped RTTs), relaxed agent scope.
template <int N>
__device__ __forceinline__ void pollN(unsigned long long* const (&p)[N],
                                      const unsigned (&tag)[N],
                                      unsigned (&res)[N], long& budget) {
    bool done[N];
#pragma unroll
    for (int i = 0; i < N; ++i) done[i] = false;
    int remaining = N;
    while (remaining > 0 && budget > 0) {
        unsigned long long v[N];
#pragma unroll
        for (int i = 0; i < N; ++i)
            if (!done[i])
                v[i] = __hip_atomic_load(p[i], __ATOMIC_RELAXED, __HIP_MEMORY_SCOPE_AGENT);
#pragma unroll
        for (int i = 0; i < N; ++i)
            if (!done[i] && (unsigned)(v[i] >> 32) == tag[i]) {
                res[i] = (unsigned)v[i]; done[i] = true; --remaining;
            }
        --budget;
    }
}

// Packed-weight layouts [wgr<8][j<P][lane<256].
// Mapping: r = wg*64 + (L&63), c = L>>6 (wave-uniform chunk).
#define N0 (8 * 80 * 256)
#define N1 (8 * 128 * 256)

__global__ void init_pack(const float* __restrict__ Wih0, const float* __restrict__ Whh0,
                          const float* __restrict__ Wih1, const float* __restrict__ Whh1,
                          unsigned* __restrict__ wp0, unsigned* __restrict__ wp1) {
    int gid = blockIdx.x * 256 + threadIdx.x;
    if (gid < N0) {
        int L = gid & 255; int j = (gid >> 8) % 80; int wg = (gid >> 8) / 80;
        int r = wg * 64 + (L & 63); int c = L >> 6; int k = c * 160 + 2 * j;
        float w0 = (k < 128) ? Wih0[r * 128 + k]     : Whh0[r * 512 + (k - 128)];
        float w1 = (k + 1 < 128) ? Wih0[r * 128 + k + 1] : Whh0[r * 512 + (k - 127)];
        wp0[gid] = pack2(w0, w1);
    } else {
        int g2 = gid - N0;
        if (g2 < N1) {
            int L = g2 & 255; int j = (g2 >> 8) % 128; int wg = (g2 >> 8) / 128;
            int r = wg * 64 + (L & 63); int c = L >> 6; int k = c * 256 + 2 * j;
            float w0 = (k < 512) ? Wih1[r * 512 + k]     : Whh1[r * 512 + (k - 512)];
            float w1 = (k + 1 < 512) ? Wih1[r * 512 + k + 1] : Whh1[r * 512 + (k - 511)];
            wp1[g2] = pack2(w0, w1);
        }
    }
}

// PW: f16-pairs per lane (80 or 128). KIN: non-recurrent width (128 or 512).
template <int PW, int KIN, int LAYER>
__device__ __forceinline__ void run_layer(
    int b0, int wgr, int L,
    const float* __restrict__ x, const float* __restrict__ noise,
    const unsigned* __restrict__ wpack,
    const float* __restrict__ bih, const float* __restrict__ bhh,
    unsigned long long* __restrict__ hbuf0,
    unsigned long long* __restrict__ hbuf1,
    const float* __restrict__ fcw, const float* __restrict__ fcb,
    float* __restrict__ out) {
    constexpr int CH = PW + 4;           // LDS chunk stride (16B-aligned)
    const int c = L >> 6;                // wave id == K-chunk id (wave-uniform)
    const int lane = L & 63;
    const int r = wgr * 64 + lane;       // lane owns a full row

    unsigned wreg[PW];
#pragma unroll
    for (int j = 0; j < PW; ++j) {
        wreg[j] = wpack[(wgr * PW + j) * 256 + L];
        asm volatile("" : "+v"(wreg[j]));
    }

    const float cb = bih[r] + bhh[r];

    __shared__ __align__(16) unsigned hv[2][4][CH];
    __shared__ float psum[4][2][64];     // [chunk][batch][row-lane]
    for (int i = L; i < 2 * 4 * CH; i += 256) ((unsigned*)hv)[i] = 0u;  // h(-1)=0
    __syncthreads();

    long budget = 2000000000L;           // hang bailout only

    // t=0 input region
    if constexpr (LAYER == 0) {
        if (L < 128) {
            int bb = L >> 6, j = L & 63;
            float2 xf = *(const float2*)(x + ((size_t)(b0 + bb) * T_STEPS) * 128 + 2 * j);
            hv[bb][j / PW][j % PW] = pack2(xf.x, xf.y);
        }
    } else {
        unsigned long long* p[2]; unsigned tg[2], res[2];
#pragma unroll
        for (int bb = 0; bb < 2; ++bb) {
            p[bb] = &hbuf0[((size_t)0 * NBATCH + (b0 + bb)) * 256 + L];
            tg[bb] = 1u;
        }
        pollN<2>(p, tg, res, budget);
#pragma unroll
        for (int bb = 0; bb < 2; ++bb) hv[bb][L >> 7][L & 127] = res[bb];
    }
    __syncthreads();

    float nz[2];
#pragma unroll
    for (int bb = 0; bb < 2; ++bb)
        nz[bb] = noise[(((size_t)(b0 + bb) * T_STEPS) * 2 + LAYER) * 512 + r];

    for (int t = 0; t < T_STEPS; ++t) {
        __builtin_amdgcn_s_setprio(1);   // compute region: outrank spinners
        const bool last = (t == T_STEPS - 1);

        // L1: prefetch h0(t+1) atoms into regs — L0 leads, tag usually set;
        // the load RTT overlaps the entire dot+reduce phase below.
        unsigned long long pf[2];
        if constexpr (LAYER == 1) {
            if (!last) {
#pragma unroll
                for (int bb = 0; bb < 2; ++bb)
                    pf[bb] = __hip_atomic_load(
                        &hbuf0[((size_t)((t + 1) & (DRING - 1)) * NBATCH + (b0 + bb)) * 256 + L],
                        __ATOMIC_RELAXED, __HIP_MEMORY_SCOPE_AGENT);
            }
        }

        // ---- dot partials: wave c handles chunk c for all 64 rows ----
#pragma unroll
        for (int bb = 0; bb < 2; ++bb) {
            const uint4* hq = (const uint4*)(&hv[bb][c][0]);   // wave-uniform address
            float a0 = 0.f, a1 = 0.f, a2 = 0.f, a3 = 0.f;
#pragma unroll
            for (int jj = 0; jj < PW / 4; ++jj) {
                uint4 hp = hq[jj];
                a0 = dot2acc(wreg[4 * jj + 0], hp.x, a0);
                a1 = dot2acc(wreg[4 * jj + 1], hp.y, a1);
                a2 = dot2acc(wreg[4 * jj + 2], hp.z, a2);
                a3 = dot2acc(wreg[4 * jj + 3], hp.w, a3);
            }
            psum[c][bb][lane] = (a0 + a1) + (a2 + a3);
        }

        // prefetch next-step inputs before the barrier (overlap HBM latency)
        float2 xf;
        float nznext[2];
        if (!last) {
            if constexpr (LAYER == 0) {
                if (L < 128) {
                    int bb = L >> 6, j = L & 63;
                    xf = *(const float2*)(x + ((size_t)(b0 + bb) * T_STEPS + (t + 1)) * 128 + 2 * j);
                }
            }
#pragma unroll
            for (int bb = 0; bb < 2; ++bb)
                nznext[bb] = noise[(((size_t)(b0 + bb) * T_STEPS + (t + 1)) * 2 + LAYER) * 512 + r];
        }

        __syncthreads();                 // psum ready; this step's hv reads complete

        // ---- cross-wave reduce + tanh + post: wave bb finishes batch bb ----
        if (c < 2) {
            const int bb = c;
            float s = psum[0][bb][lane] + psum[1][bb][lane] +
                      psum[2][bb][lane] + psum[3][bb][lane];
            float nzsel = (c == 0) ? nz[0] : nz[1];
            float h = fast_tanh(s + cb + nzsel);
            float hnb = __shfl_down(h, 1);
            if ((lane & 1) == 0) {
                unsigned pv = pack2(h, hnb);
                unsigned long long atom =
                    ((unsigned long long)(unsigned)(t + 1) << 32) | (unsigned long long)pv;
                const int pr = r >> 1;   // pair index wgr*32 + lane/2
                if constexpr (LAYER == 0)
                    __hip_atomic_store(
                        &hbuf0[((size_t)(t & (DRING - 1)) * NBATCH + (b0 + bb)) * 256 + pr],
                        atom, __ATOMIC_RELAXED, __HIP_MEMORY_SCOPE_AGENT);
                else
                    __hip_atomic_store(
                        &hbuf1[((size_t)(t & 3) * NBATCH + (b0 + bb)) * 256 + pr],
                        atom, __ATOMIC_RELAXED, __HIP_MEMORY_SCOPE_AGENT);
            }
        }

        __builtin_amdgcn_s_setprio(0);   // spin region: yield issue slots

        if (last) break;

        nz[0] = nznext[0]; nz[1] = nznext[1];

        // ---- gather h(t) back, place into hv ----
        if constexpr (LAYER == 0) {
            unsigned long long* p[2]; unsigned tg[2], res[2];
#pragma unroll
            for (int bb = 0; bb < 2; ++bb) {
                p[bb] = &hbuf0[((size_t)(t & (DRING - 1)) * NBATCH + (b0 + bb)) * 256 + L];
                tg[bb] = (unsigned)(t + 1);
            }
            pollN<2>(p, tg, res, budget);
            __builtin_amdgcn_s_setprio(1);
#pragma unroll
            for (int bb = 0; bb < 2; ++bb) {
                int q = 64 + L;                          // recurrent pair index
                hv[bb][q / PW][q % PW] = res[bb];
            }
            if (L < 128) {
                int bb = L >> 6, j = L & 63;
                hv[bb][j / PW][j % PW] = pack2(xf.x, xf.y);
            }
        } else {
            // blocking poll: only the 2 self-recurrence atoms
            unsigned long long* p[2]; unsigned tg[2], res[2];
#pragma unroll
            for (int bb = 0; bb < 2; ++bb) {
                p[bb] = &hbuf1[((size_t)(t & 3) * NBATCH + (b0 + bb)) * 256 + L];
                tg[bb] = (unsigned)(t + 1);              // h1(t) self-recurrence
            }
            pollN<2>(p, tg, res, budget);

            // h0(t+1): use the prefetched atom if its tag landed, else poll
            unsigned h0res[2];
#pragma unroll
            for (int bb = 0; bb < 2; ++bb) {
                unsigned long long v = pf[bb];
                unsigned long long* ptr =
                    &hbuf0[((size_t)((t + 1) & (DRING - 1)) * NBATCH + (b0 + bb)) * 256 + L];
                while ((unsigned)(v >> 32) != (unsigned)(t + 2) && budget > 0) {
                    v = __hip_atomic_load(ptr, __ATOMIC_RELAXED, __HIP_MEMORY_SCOPE_AGENT);
                    --budget;
                }
                h0res[bb] = (unsigned)v;
            }
            __builtin_amdgcn_s_setprio(1);
#pragma unroll
            for (int bb = 0; bb < 2; ++bb) {
                int q = 256 + L;                         // h1 pairs -> chunks 2,3
                hv[bb][q >> 7][q & 127] = res[bb];
                hv[bb][L >> 7][L & 127] = h0res[bb];     // h0 pairs -> chunks 0,1
            }
        }
        __syncthreads();
        __builtin_amdgcn_s_setprio(0);
    }

    __builtin_amdgcn_s_setprio(0);

    if constexpr (LAYER == 1) {
        __shared__ float hs[2][512];
        __shared__ float part[2][256];
        if (wgr == 0) {                  // FC epilogue: out = h1(T-1) @ fc_w^T + fc_b
            unsigned long long* p[2]; unsigned tg[2], res[2];
#pragma unroll
            for (int bb = 0; bb < 2; ++bb) {
                p[bb] = &hbuf1[((size_t)((T_STEPS - 1) & 3) * NBATCH + (b0 + bb)) * 256 + L];
                tg[bb] = (unsigned)T_STEPS;
            }
            pollN<2>(p, tg, res, budget);
#pragma unroll
            for (int bb = 0; bb < 2; ++bb) {
                half2v h2 = __builtin_bit_cast(half2v, res[bb]);
                hs[bb][2 * L] = (float)h2.x; hs[bb][2 * L + 1] = (float)h2.y;
            }
            __syncthreads();
            const int o = L & 31, seg = L >> 5;          // 32 outputs x 8 k-segments
#pragma unroll
            for (int bb = 0; bb < 2; ++bb) {
                const float* wr = fcw + o * 512 + seg * 64;
                const float* hr = &hs[bb][seg * 64];
                float a = 0.f;
#pragma unroll 16
                for (int k = 0; k < 64; ++k) a = fmaf(wr[k], hr[k], a);
                part[bb][L] = a;
            }
            __syncthreads();
            if (L < 64) {
                int bb = L >> 5, oo = L & 31;
                float s = fcb[oo];
#pragma unroll
                for (int sgi = 0; sgi < 8; ++sgi) s += part[bb][sgi * 32 + oo];
                out[(b0 + bb) * 32 + oo] = s;
            }
        }
    }
}

__global__ __launch_bounds__(256, 2)
void rnn_dual(const float* __restrict__ x, const float* __restrict__ noise,
              const unsigned* __restrict__ wp0, const unsigned* __restrict__ wp1,
              const float* __restrict__ bih0, const float* __restrict__ bhh0,
              const float* __restrict__ bih1, const float* __restrict__ bhh1,
              const float* __restrict__ fcw, const float* __restrict__ fcb,
              unsigned long long* __restrict__ hbuf0,
              unsigned long long* __restrict__ hbuf1,
              float* __restrict__ out) {
    const int L = threadIdx.x;
    const int gid = blockIdx.x;
    const int layer = gid & 1;           // XCD = (2g+layer)%8 under rr dispatch:
    const int rest = gid >> 1;           //   all 8 row-WGs of (g,layer) share an XCD
    const int g = rest & 31;
    const int wgr = rest >> 5;
    const int b0 = g * 2;
    if (layer == 0)
        run_layer<80, 128, 0>(b0, wgr, L, x, noise, wp0, bih0, bhh0,
                              hbuf0, hbuf1, nullptr, nullptr, nullptr);
    else
        run_layer<128, 512, 1>(b0, wgr, L, x, noise, wp1, bih1, bhh1,
                               hbuf0, hbuf1, fcw, fcb, out);
}

extern "C" void kernel_launch(void* const* d_in, const int* in_sizes, int n_in,
                              void* d_out, int out_size, void* d_ws, size_t ws_size,
                              hipStream_t stream) {
    const float* x     = (const float*)d_in[0];
    const float* noise = (const float*)d_in[1];
    const float* Wih0  = (const float*)d_in[2];
    const float* Wih1  = (const float*)d_in[3];
    const float* Whh0  = (const float*)d_in[4];
    const float* Whh1  = (const float*)d_in[5];
    const float* bih0  = (const float*)d_in[6];
    const float* bih1  = (const float*)d_in[7];
    const float* bhh0  = (const float*)d_in[8];
    const float* bhh1  = (const float*)d_in[9];
    const float* fcw   = (const float*)d_in[10];
    const float* fcb   = (const float*)d_in[11];
    float* out = (float*)d_out;

    char* ws = (char*)d_ws;
    size_t o = 0;
    unsigned* wp0 = (unsigned*)(ws + o); o += (size_t)N0 * 4;   // 640 KB
    unsigned* wp1 = (unsigned*)(ws + o); o += (size_t)N1 * 4;   // 1 MB
    unsigned long long* hb0 = (unsigned long long*)(ws + o);
    o += (size_t)DRING * NBATCH * 256 * 8;                      // 33.5 MB ring
    unsigned long long* hb1 = (unsigned long long*)(ws + o);
    o += (size_t)4 * NBATCH * 256 * 8;                          // 512 KB ring

    const int initBlocks = (N0 + N1 + 255) / 256;
    init_pack<<<initBlocks, 256, 0, stream>>>(Wih0, Whh0, Wih1, Whh1, wp0, wp1);
    rnn_dual<<<512, 256, 0, stream>>>(x, noise, wp0, wp1, bih0, bhh0, bih1, bhh1,
                                      fcw, fcb, hb0, hb1, out);
}

// Round 3
// 1385.083 us; speedup vs baseline: 1.1959x; 1.1275x over previous
//
#include <hip/hip_runtime.h>

// ---------------------------------------------------------------------------
// Two-layer tanh RNN — persistent cluster kernel, round 5: big-WG restructure.
// B=64, T=512, H=512, I=128, W_OUT=32. fp32 in/out, f16-pair internal, fp32 acc.
//
// 256 WGs x 1024 threads, 1 WG/CU (VGPR<=128 via launch_bounds(1024,4)):
//   cluster cl = gid&63 (layer = cl>>5, batch-pair = cl&31), sibling s = gid>>6.
//   gid = cl + 64*s  => gid%8 == cl%8: all 4 siblings AND the matching other-
//   layer cluster share one XCD (rr dispatch) — exchange stays XCD-L2-local.
// Per WG: 8 K-chunks x 128 rows; lane L: chunk c=L>>7, row rw=L&127,
//   r = s*128+rw. Weights in regs: PW=40 (L0: K=640) / 64 (L1: K=1024) pairs.
//   hv reads in dots are wave-uniform (broadcast). psum[8][2][128] in LDS;
//   reduce lanes 0-255 finish rows (tanh+pack+post), write OWN pairs to LDS
//   hv directly (no global RTT); 3 sibling quarters gathered via tagged atoms.
// Roles per step (wave-uniform): waves 0-3 reduce/post; L0: waves 4-9 sib-
//   gather, 10-11 x-prefetch+write; L1: waves 2-7 h1-sib-gather, 8-15 h0
//   prefetch+gather. All 16 waves do dots.
// Ring-overwrite guard: L0 free-runs (own CUs) => could lap DRING=256. L1
//   (s==0,lane 0) posts prog=t-1 after barrier#2 (proves all sibs consumed
//   h0 slot t&255); L0 throttles when lead > 192 (overwrite horizon 257).
// Exchange: 64-bit {tag|f16pair} atoms, RELAXED agent scope (as prior rounds).
// FC epilogue in L1 s==0 WGs.
// ---------------------------------------------------------------------------

#define T_STEPS 512
#define NBATCH  64
#define DRING   256
#define THR_LEAD 192

typedef _Float16 half2v __attribute__((ext_vector_type(2)));

__device__ __forceinline__ unsigned pack2(float a, float b) {
    _Float16 fa = (_Float16)a, fb = (_Float16)b;
    unsigned short ua = __builtin_bit_cast(unsigned short, fa);
    unsigned short ub = __builtin_bit_cast(unsigned short, fb);
    return (unsigned)ua | ((unsigned)ub << 16);
}

__device__ __forceinline__ float dot2acc(unsigned w, unsigned h, float acc) {
#if __has_builtin(__builtin_amdgcn_fdot2)
    return __builtin_amdgcn_fdot2(__builtin_bit_cast(half2v, w),
                                  __builtin_bit_cast(half2v, h), acc, false);
#else
    half2v wv = __builtin_bit_cast(half2v, w);
    half2v hv = __builtin_bit_cast(half2v, h);
    acc = fmaf((float)wv.x, (float)hv.x, acc);
    return fmaf((float)wv.y, (float)hv.y, acc);
#endif
}

__device__ __forceinline__ float fast_tanh(float xv) {
    float e2 = __builtin_amdgcn_exp2f(xv * 2.885390082f);
    return 1.f - 2.f * __builtin_amdgcn_rcpf(e2 + 1.f);
}

// Poll N tagged atoms concurrently, relaxed agent scope.
template <int N>
__device__ __forceinline__ void pollN(unsigned long long* const (&p)[N],
                                      const unsigned (&tag)[N],
                                      unsigned (&res)[N], long& budget) {
    bool done[N];
#pragma unroll
    for (int i = 0; i < N; ++i) done[i] = false;
    int remaining = N;
    while (remaining > 0 && budget > 0) {
        unsigned long long v[N];
#pragma unroll
        for (int i = 0; i < N; ++i)
            if (!done[i])
                v[i] = __hip_atomic_load(p[i], __ATOMIC_RELAXED, __HIP_MEMORY_SCOPE_AGENT);
#pragma unroll
        for (int i = 0; i < N; ++i)
            if (!done[i] && (unsigned)(v[i] >> 32) == tag[i]) {
                res[i] = (unsigned)v[i]; done[i] = true; --remaining;
            }
        --budget;
    }
}

// Packed-weight layouts [s<4][j<PW][lane<1024].
// Mapping: r = s*128 + (L&127), c = L>>7 (8 chunks), k = c*(K/8) + 2*j.
#define N0 (4 * 40 * 1024)
#define N1 (4 * 64 * 1024)

__global__ void init_pack(const float* __restrict__ Wih0, const float* __restrict__ Whh0,
                          const float* __restrict__ Wih1, const float* __restrict__ Whh1,
                          unsigned* __restrict__ wp0, unsigned* __restrict__ wp1) {
    int gid = blockIdx.x * 256 + threadIdx.x;
    if (gid < N0) {
        int L = gid & 1023; int rest = gid >> 10; int j = rest % 40; int s = rest / 40;
        int r = s * 128 + (L & 127); int c = L >> 7; int k = c * 80 + 2 * j;
        float w0 = (k < 128)     ? Wih0[r * 128 + k]     : Whh0[r * 512 + (k - 128)];
        float w1 = (k + 1 < 128) ? Wih0[r * 128 + k + 1] : Whh0[r * 512 + (k - 127)];
        wp0[gid] = pack2(w0, w1);
    } else {
        int g2 = gid - N0;
        if (g2 < N1) {
            int L = g2 & 1023; int rest = g2 >> 10; int j = rest % 64; int s = rest / 64;
            int r = s * 128 + (L & 127); int c = L >> 7; int k = c * 128 + 2 * j;
            float w0 = (k < 512)     ? Wih1[r * 512 + k]     : Whh1[r * 512 + (k - 512)];
            float w1 = (k + 1 < 512) ? Wih1[r * 512 + k + 1] : Whh1[r * 512 + (k - 511)];
            wp1[g2] = pack2(w0, w1);
        }
    }
}

// PW: f16-pairs per lane per chunk-row (40 for L0, 64 for L1).
template <int PW, int LAYER>
__device__ __forceinline__ void run_layer(
    int b0, int s, int L, int pair,
    const float* __restrict__ x, const float* __restrict__ noise,
    const unsigned* __restrict__ wpack,
    const float* __restrict__ bih, const float* __restrict__ bhh,
    unsigned long long* __restrict__ hbuf0,
    unsigned long long* __restrict__ hbuf1,
    int* __restrict__ prog,
    const float* __restrict__ fcw, const float* __restrict__ fcb,
    float* __restrict__ out) {
    constexpr int CH = PW + 4;           // LDS chunk stride, 16B-aligned
    const int c = L >> 7;                // chunk 0..7 (wave-uniform: 2 waves/chunk)
    const int rw = L & 127;              // row within this WG's quarter

    unsigned wreg[PW];
#pragma unroll
    for (int j = 0; j < PW; ++j) {
        wreg[j] = wpack[(s * PW + j) * 1024 + L];
        asm volatile("" : "+v"(wreg[j]));
    }

    __shared__ __align__(16) unsigned hv[2][8][CH];
    __shared__ float psum[8][2][128];    // [chunk][batch][row]
    for (int i = L; i < 2 * 8 * CH; i += 1024) ((unsigned*)hv)[i] = 0u;  // h(-1)=0

    long budget = 2000000000L;           // hang bailout only

    float cb = 0.f;
    float nz[2] = {0.f, 0.f};
    if (L < 256) {                       // reduce-role constants (row = s*128+(L&127))
        int rr = s * 128 + (L & 127);
        cb = bih[rr] + bhh[rr];
#pragma unroll
        for (int bb = 0; bb < 2; ++bb)
            nz[bb] = noise[(((size_t)(b0 + bb) * T_STEPS) * 2 + LAYER) * 512 + rr];
    }

    __syncthreads();                     // zero-fill done

    // t=0 inputs
    if constexpr (LAYER == 0) {
        if (L >= 640 && L < 768) {
            int idx = L - 640; int xb = idx >> 6; int j = idx & 63;
            float2 xf = *(const float2*)(x + ((size_t)(b0 + xb) * T_STEPS) * 128 + 2 * j);
            hv[xb][j / PW][j % PW] = pack2(xf.x, xf.y);
        }
    } else {
        if (L == 0 && s == 0)            // reset progress before any L0 throttle read
            __hip_atomic_store(&prog[pair], 0, __ATOMIC_RELAXED, __HIP_MEMORY_SCOPE_AGENT);
        if (L >= 512) {
            int idx = L - 512; int bb = idx >> 8; int p0 = idx & 255;
            unsigned long long* p[1]; unsigned tg[1], res[1];
            p[0] = &hbuf0[((size_t)0 * NBATCH + (b0 + bb)) * 256 + p0];
            tg[0] = 1u;
            pollN<1>(p, tg, res, budget);
            hv[bb][p0 / PW][p0 % PW] = res[0];
        }
    }
    __syncthreads();

    int known = 0;

    for (int t = 0; t < T_STEPS; ++t) {
        __builtin_amdgcn_s_setprio(1);
        const bool last = (t == T_STEPS - 1);

        // ---- top-of-step prefetches (RTTs overlap the dot phase) ----
        unsigned long long pf = 0;
        if constexpr (LAYER == 1) {
            if (!last && L >= 512) {     // h0(t+1): L0 leads, tag usually already set
                int idx = L - 512; int bb = idx >> 8; int p0 = idx & 255;
                pf = __hip_atomic_load(
                    &hbuf0[((size_t)((t + 1) & (DRING - 1)) * NBATCH + (b0 + bb)) * 256 + p0],
                    __ATOMIC_RELAXED, __HIP_MEMORY_SCOPE_AGENT);
            }
        }
        float2 xf;
        if constexpr (LAYER == 0) {
            if (!last && L >= 640 && L < 768) {
                int idx = L - 640; int xb = idx >> 6; int j = idx & 63;
                xf = *(const float2*)(x + ((size_t)(b0 + xb) * T_STEPS + (t + 1)) * 128 + 2 * j);
            }
        }
        float nznext[2] = {0.f, 0.f};
        if (!last && L < 256) {
            int rr = s * 128 + (L & 127);
#pragma unroll
            for (int bb = 0; bb < 2; ++bb)
                nznext[bb] = noise[(((size_t)(b0 + bb) * T_STEPS + (t + 1)) * 2 + LAYER) * 512 + rr];
        }

        // ---- L0 ring-overwrite throttle (lead cap 192 < horizon 257) ----
        if constexpr (LAYER == 0) {
            if (t - known > THR_LEAD) {
                __builtin_amdgcn_s_setprio(0);
                while (t - known > THR_LEAD && budget > 0) {
                    known = __hip_atomic_load(&prog[pair], __ATOMIC_RELAXED,
                                              __HIP_MEMORY_SCOPE_AGENT);
                    --budget;
                }
                __builtin_amdgcn_s_setprio(1);
            }
        }

        // ---- dots: lane (c, rw) x both batches, wave-uniform hv reads ----
#pragma unroll
        for (int bb = 0; bb < 2; ++bb) {
            const uint4* hq = (const uint4*)(&hv[bb][c][0]);
            float a0 = 0.f, a1 = 0.f, a2 = 0.f, a3 = 0.f;
#pragma unroll
            for (int jj = 0; jj < PW / 4; ++jj) {
                uint4 hp = hq[jj];
                a0 = dot2acc(wreg[4 * jj + 0], hp.x, a0);
                a1 = dot2acc(wreg[4 * jj + 1], hp.y, a1);
                a2 = dot2acc(wreg[4 * jj + 2], hp.z, a2);
                a3 = dot2acc(wreg[4 * jj + 3], hp.w, a3);
            }
            psum[c][bb][rw] = (a0 + a1) + (a2 + a3);
        }

        __syncthreads();                 // barrier 1: psum ready, hv reads done

        // ---- reduce + tanh + post + own-LDS write: lanes 0..255 ----
        if (L < 256) {
            int bb = L >> 7; int rr = L & 127;
            float s8 = ((psum[0][bb][rr] + psum[1][bb][rr]) +
                        (psum[2][bb][rr] + psum[3][bb][rr])) +
                       ((psum[4][bb][rr] + psum[5][bb][rr]) +
                        (psum[6][bb][rr] + psum[7][bb][rr]));
            float nzsel = (bb == 0) ? nz[0] : nz[1];
            float h = fast_tanh(s8 + cb + nzsel);
            float hnb = __shfl_down(h, 1);
            if ((L & 1) == 0) {
                unsigned pv = pack2(h, hnb);
                int pr = s * 64 + (rr >> 1);            // global pair 0..255
                unsigned long long atom =
                    ((unsigned long long)(unsigned)(t + 1) << 32) | (unsigned long long)pv;
                if constexpr (LAYER == 0)
                    __hip_atomic_store(
                        &hbuf0[((size_t)(t & (DRING - 1)) * NBATCH + (b0 + bb)) * 256 + pr],
                        atom, __ATOMIC_RELAXED, __HIP_MEMORY_SCOPE_AGENT);
                else
                    __hip_atomic_store(
                        &hbuf1[((size_t)(t & 3) * NBATCH + (b0 + bb)) * 256 + pr],
                        atom, __ATOMIC_RELAXED, __HIP_MEMORY_SCOPE_AGENT);
                int q = (LAYER == 0 ? 64 : 256) + pr;   // own pairs direct to LDS
                hv[bb][q / PW][q % PW] = pv;
            }
        }

        __builtin_amdgcn_s_setprio(0);
        if (last) break;

        nz[0] = nznext[0]; nz[1] = nznext[1];

        // ---- gather sibling quarters (+x / +h0) into hv ----
        if constexpr (LAYER == 0) {
            if (L >= 256 && L < 640) {   // 384 lanes: 3 sib quarters x 2 batches
                int idx = L - 256; int bb = idx / 192; int m = idx % 192;
                int p2 = (m < s * 64) ? m : m + 64;
                unsigned long long* p[1]; unsigned tg[1], res[1];
                p[0] = &hbuf0[((size_t)(t & (DRING - 1)) * NBATCH + (b0 + bb)) * 256 + p2];
                tg[0] = (unsigned)(t + 1);
                pollN<1>(p, tg, res, budget);
                int q = 64 + p2;
                hv[bb][q / PW][q % PW] = res[0];
            }
            if (L >= 640 && L < 768) {   // x(t+1) pairs
                int idx = L - 640; int xb = idx >> 6; int j = idx & 63;
                hv[xb][j / PW][j % PW] = pack2(xf.x, xf.y);
            }
        } else {
            if (L >= 128 && L < 512) {   // 384 lanes: h1 sib quarters
                int idx = L - 128; int bb = idx / 192; int m = idx % 192;
                int p2 = (m < s * 64) ? m : m + 64;
                unsigned long long* p[1]; unsigned tg[1], res[1];
                p[0] = &hbuf1[((size_t)(t & 3) * NBATCH + (b0 + bb)) * 256 + p2];
                tg[0] = (unsigned)(t + 1);
                pollN<1>(p, tg, res, budget);
                int q = 256 + p2;
                hv[bb][q / PW][q % PW] = res[0];
            }
            if (L >= 512) {              // h0(t+1): check prefetch, else poll
                int idx = L - 512; int bb = idx >> 8; int p0 = idx & 255;
                unsigned long long v = pf;
                unsigned long long* ptr =
                    &hbuf0[((size_t)((t + 1) & (DRING - 1)) * NBATCH + (b0 + bb)) * 256 + p0];
                while ((unsigned)(v >> 32) != (unsigned)(t + 2) && budget > 0) {
                    v = __hip_atomic_load(ptr, __ATOMIC_RELAXED, __HIP_MEMORY_SCOPE_AGENT);
                    --budget;
                }
                hv[bb][p0 / PW][p0 % PW] = (unsigned)v;
            }
        }
        __syncthreads();                 // barrier 2: hv(t+1) complete

        // prog = t-1: all sibs provably consumed h0 slot t&255 by now
        if constexpr (LAYER == 1) {
            if (L == 0 && s == 0 && t > 0)
                __hip_atomic_store(&prog[pair], t - 1, __ATOMIC_RELAXED,
                                   __HIP_MEMORY_SCOPE_AGENT);
        }
    }

    __builtin_amdgcn_s_setprio(0);

    if constexpr (LAYER == 1) {
        if (s == 0) {                    // FC epilogue: out = h1(T-1) @ fc_w^T + fc_b
            __shared__ float hs[2][512];
            __shared__ float part[2][512];
            if (L < 512) {
                int bb = L >> 8; int pr = L & 255;
                unsigned long long* p[1]; unsigned tg[1], res[1];
                p[0] = &hbuf1[((size_t)((T_STEPS - 1) & 3) * NBATCH + (b0 + bb)) * 256 + pr];
                tg[0] = (unsigned)T_STEPS;
                pollN<1>(p, tg, res, budget);
                half2v h2 = __builtin_bit_cast(half2v, res[0]);
                hs[bb][2 * pr] = (float)h2.x; hs[bb][2 * pr + 1] = (float)h2.y;
            }
            __syncthreads();
            {
                int bb = L >> 9; int rest = L & 511; int o = rest & 31; int seg = rest >> 5;
                const float* wr = fcw + o * 512 + seg * 32;
                const float* hr = &hs[bb][seg * 32];
                float a = 0.f;
#pragma unroll
                for (int k = 0; k < 32; ++k) a = fmaf(wr[k], hr[k], a);
                part[bb][rest] = a;
            }
            __syncthreads();
            if (L < 64) {
                int bb = L >> 5; int o = L & 31;
                float ssum = fcb[o];
#pragma unroll
                for (int sgi = 0; sgi < 16; ++sgi) ssum += part[bb][sgi * 32 + o];
                out[(b0 + bb) * 32 + o] = ssum;
            }
        }
    }
}

__global__ __launch_bounds__(1024, 4)
void rnn_dual(const float* __restrict__ x, const float* __restrict__ noise,
              const unsigned* __restrict__ wp0, const unsigned* __restrict__ wp1,
              const float* __restrict__ bih0, const float* __restrict__ bhh0,
              const float* __restrict__ bih1, const float* __restrict__ bhh1,
              const float* __restrict__ fcw, const float* __restrict__ fcb,
              unsigned long long* __restrict__ hbuf0,
              unsigned long long* __restrict__ hbuf1,
              int* __restrict__ prog,
              float* __restrict__ out) {
    const int L = threadIdx.x;
    const int gid = blockIdx.x;
    const int cl = gid & 63;             // cluster: layer*32 + pair
    const int s = gid >> 6;              // sibling quarter 0..3
    const int layer = cl >> 5;
    const int pair = cl & 31;
    const int b0 = pair * 2;             // gid%8 == cl%8: cluster+other-layer co-XCD
    if (layer == 0)
        run_layer<40, 0>(b0, s, L, pair, x, noise, wp0, bih0, bhh0,
                         hbuf0, hbuf1, prog, nullptr, nullptr, nullptr);
    else
        run_layer<64, 1>(b0, s, L, pair, x, noise, wp1, bih1, bhh1,
                         hbuf0, hbuf1, prog, fcw, fcb, out);
}

extern "C" void kernel_launch(void* const* d_in, const int* in_sizes, int n_in,
                              void* d_out, int out_size, void* d_ws, size_t ws_size,
                              hipStream_t stream) {
    const float* x     = (const float*)d_in[0];
    const float* noise = (const float*)d_in[1];
    const float* Wih0  = (const float*)d_in[2];
    const float* Wih1  = (const float*)d_in[3];
    const float* Whh0  = (const float*)d_in[4];
    const float* Whh1  = (const float*)d_in[5];
    const float* bih0  = (const float*)d_in[6];
    const float* bih1  = (const float*)d_in[7];
    const float* bhh0  = (const float*)d_in[8];
    const float* bhh1  = (const float*)d_in[9];
    const float* fcw   = (const float*)d_in[10];
    const float* fcb   = (const float*)d_in[11];
    float* out = (float*)d_out;

    char* ws = (char*)d_ws;
    size_t o = 0;
    unsigned* wp0 = (unsigned*)(ws + o); o += (size_t)N0 * 4;   // 640 KB
    unsigned* wp1 = (unsigned*)(ws + o); o += (size_t)N1 * 4;   // 1 MB
    unsigned long long* hb0 = (unsigned long long*)(ws + o);
    o += (size_t)DRING * NBATCH * 256 * 8;                      // 33.5 MB ring
    unsigned long long* hb1 = (unsigned long long*)(ws + o);
    o += (size_t)4 * NBATCH * 256 * 8;                          // 512 KB ring
    int* prog = (int*)(ws + o); o += 32 * sizeof(int);          // L1 progress

    const int initBlocks = (N0 + N1 + 255) / 256;
    init_pack<<<initBlocks, 256, 0, stream>>>(Wih0, Whh0, Wih1, Whh1, wp0, wp1);
    rnn_dual<<<256, 1024, 0, stream>>>(x, noise, wp0, wp1, bih0, bhh0, bih1, bhh1,
                                       fcw, fcb, hb0, hb1, prog, out);
}